// Round 6
// baseline (198.483 us; speedup 1.0000x reference)
//
#include <hip/hip_runtime.h>
#include <cfloat>
#include <math.h>

#define N_TOK 32768
#define DIM   256
#define MCODE 1024

typedef unsigned short u16;
typedef unsigned long long u64;
typedef __attribute__((ext_vector_type(8))) short short8;
typedef __attribute__((ext_vector_type(4))) float f32x4;

constexpr float DECAY_ = 0.999f;
constexpr float OMD_   = (float)(1.0 - 0.999);   // match jax double->f32 promotion
constexpr float EPS_   = 1e-5f;
constexpr float MEPS_  = (float)(1024 * 1e-5);   // M * EPS in double, then f32

// ---- workspace layout (float offsets) ----
// TOTAL = 364544 floats = 1,458,176 B. MUST stay <= 3,284,992 B (Round-1-proven
// ws_size bound) — overflow corrupts harness pristine copies (Round-2 failure).
constexpr int WS_EH   = 0;        // eh[1024*256] bf16 -> 131072 float slots
constexpr int WS_EL   = 131072;   // el           -> 131072
constexpr int WS_ESQ  = 262144;   // esq[1024]
constexpr int WS_CNTI = 263168;   // int counts[1024] (zeroed in setup)
constexpr int WS_BI   = 264192;   // int bi[32768]
constexpr int WS_LP   = 296960;   // loss partials[2048]
constexpr int WS_KEY  = 299008;   // u64 keys[32768] (8B-aligned)

// ---- output layout (float offsets) ----
constexpr int OUT_Q        = 0;
constexpr int OUT_COMMIT   = 8388608;
constexpr int OUT_CODEBOOK = 8388609;
constexpr int OUT_PERP     = 8388610;
constexpr int OUT_NE       = 8388611;
constexpr int OUT_NC       = 8650755;
constexpr int OUT_NW       = 8651779;

static __device__ __forceinline__ u16 f2bf(float f) {
    unsigned u = __float_as_uint(f);
    unsigned r = (u + 0x7fff + ((u >> 16) & 1)) >> 16;   // rn-even
    return (u16)r;
}
static __device__ __forceinline__ float bf2f(u16 h) {
    return __uint_as_float(((unsigned)h) << 16);
}
static __device__ __forceinline__ void gl2lds16(const u16* g, char* l) {
    __builtin_amdgcn_global_load_lds(
        (const __attribute__((address_space(1))) unsigned int*)g,
        (__attribute__((address_space(3))) unsigned int*)l, 16, 0, 0);
}
// monotone float->uint map: a<b  <=>  map(a)<map(b)  (finite floats)
static __device__ __forceinline__ unsigned fmap(float f) {
    unsigned u = __float_as_uint(f);
    return (u & 0x80000000u) ? ~u : (u | 0x80000000u);
}

// split fp32 -> (bf16 hi, bf16 residual) in MFMA-fragment global order:
// dst[wave*512 + lane*8 + j] <-> src[row=(wave>>6)*128+(wave&7)*16+(lane&15)]
//                                   [k=((wave>>3)&7)*32+(lane>>4)*8+j]
static __device__ __forceinline__ void pack_wave(const float* __restrict__ src,
                                                 u16* __restrict__ dh,
                                                 u16* __restrict__ dl,
                                                 int wave_id, int lane) {
    int rb = wave_id >> 6, kc = (wave_id >> 3) & 7, t = wave_id & 7;
    int row = rb * 128 + t * 16 + (lane & 15);
    int k   = kc * 32 + (lane >> 4) * 8;
    const float* s = &src[row * DIM + k];
    float4 v0 = *(const float4*)s, v1 = *(const float4*)(s + 4);
    float vv[8] = {v0.x, v0.y, v0.z, v0.w, v1.x, v1.y, v1.z, v1.w};
    short8 hv, lv;
#pragma unroll
    for (int j = 0; j < 8; ++j) {
        float v = vv[j];
        u16 h = f2bf(v);
        float r = v - bf2f(h);
        hv[j] = (short)h;
        lv[j] = (short)f2bf(r);
    }
    size_t o = (size_t)wave_id * 512 + lane * 8;
    *(short8*)&dh[o] = hv;
    *(short8*)&dl[o] = lv;
}

// fused setup: pack x (blocks 0..4095), pack e (+0..127), esq (+128..383),
// keys init (+384..511), int counts zero (+512). All independent. (R5-proven)
__global__ __launch_bounds__(256) void vq_setup(const float* __restrict__ x,
                                                const float* __restrict__ emb,
                                                u16* __restrict__ xh,
                                                u16* __restrict__ xl,
                                                u16* __restrict__ eh,
                                                u16* __restrict__ el,
                                                float* __restrict__ esq,
                                                u64* __restrict__ keys,
                                                int* __restrict__ cnti) {
    const int b = blockIdx.x, tid = threadIdx.x;
    const int lane = tid & 63, w = tid >> 6;
    if (b < 4096) { pack_wave(x, xh, xl, b * 4 + w, lane); return; }
    const int p = b - 4096;
    if (p < 128) {
        pack_wave(emb, eh, el, p * 4 + w, lane);
    } else if (p < 384) {
        int c = (p - 128) * 4 + w;
        float4 v = *(const float4*)&emb[c * DIM + lane * 4];
        float s = v.x * v.x + v.y * v.y + v.z * v.z + v.w * v.w;
#pragma unroll
        for (int off = 32; off; off >>= 1) s += __shfl_xor(s, off, 64);
        if (lane == 0) esq[c] = s;
    } else if (p < 512) {
        keys[(p - 384) * 256 + tid] = ~0ULL;
    } else {
#pragma unroll
        for (int i = 0; i < 4; ++i) cnti[i * 256 + tid] = 0;
    }
}

// main MFMA scores+argmin: 2048 blocks; swizzled so all 8 col-splits of a
// row-block land on the SAME XCD (idx%8 == rb%8) -> x tiles from per-XCD L2
// (R4-proven: FETCH 132->20.5 MB).
// block = 128 rows x 128 cols, 4 waves 2x2, wave = 4x4 grid of 16x16x32.
// dot = xh*eh + xh*el + xl*eh (3 MFMA); dist = esq[c] - 2*dot.
__global__ __launch_bounds__(256) void vq_scores_mfma(const u16* __restrict__ xh,
                                                      const u16* __restrict__ xl,
                                                      const u16* __restrict__ eh,
                                                      const u16* __restrict__ el,
                                                      const float* __restrict__ esq,
                                                      u64* __restrict__ keys) {
    __shared__ __align__(16) char smem[33792];
    const int tid  = threadIdx.x;
    const int lane = tid & 63, w = tid >> 6;
    const int wm = w & 1, wn = w >> 1;
    const int raw = blockIdx.x;
    const int rb = (raw >> 6) * 8 + (raw & 7);
    const int cs = (raw >> 3) & 7;

    const u16* gb[4] = {xh + (size_t)rb * 32768, xl + (size_t)rb * 32768,
                        eh + (size_t)cs * 32768, el + (size_t)cs * 32768};

    const short8* Ah = (const short8*)(smem);
    const short8* Al = (const short8*)(smem + 8192);
    const short8* Bh = (const short8*)(smem + 16384);
    const short8* Bl = (const short8*)(smem + 24576);

    f32x4 acc[4][4];
#pragma unroll
    for (int i = 0; i < 4; ++i)
#pragma unroll
        for (int j = 0; j < 4; ++j) acc[i][j] = (f32x4)0.f;

    for (int kc = 0; kc < 8; ++kc) {
        __syncthreads();   // previous chunk's frag reads done before overwrite
        {
            const u16* g = gb[w] + kc * 4096 + lane * 8;
            char* l = smem + w * 8192;
#pragma unroll
            for (int s2 = 0; s2 < 8; ++s2)
                gl2lds16(g + s2 * 512, l + s2 * 1024);
        }
        __syncthreads();   // drains vmcnt (incl. global_load_lds) + barrier

        short8 ah[4], al[4];
#pragma unroll
        for (int tm = 0; tm < 4; ++tm) {
            int idx = (wm * 4 + tm) * 64 + lane;
            ah[tm] = Ah[idx];
            al[tm] = Al[idx];
        }
#pragma unroll
        for (int tn = 0; tn < 4; ++tn) {
            int bidx = (wn * 4 + tn) * 64 + lane;
            short8 bh = Bh[bidx], bl = Bl[bidx];
#pragma unroll
            for (int tm = 0; tm < 4; ++tm) {
                acc[tm][tn] = __builtin_amdgcn_mfma_f32_16x16x32_bf16(ah[tm], bh, acc[tm][tn], 0, 0, 0);
                acc[tm][tn] = __builtin_amdgcn_mfma_f32_16x16x32_bf16(al[tm], bh, acc[tm][tn], 0, 0, 0);
                acc[tm][tn] = __builtin_amdgcn_mfma_f32_16x16x32_bf16(ah[tm], bl, acc[tm][tn], 0, 0, 0);
            }
        }
    }

    // epilogue: dist = esq - 2*acc, per-row argmin.
    // C/D layout: col = lane&15, row = (lane>>4)*4 + reg (m89/m91-verified)
    __syncthreads();
    float* cv = (float*)smem;            // [128 rows][33 slots] pad -> conflict-free
    int*   ci = (int*)(smem + 16896);
    const int ln = lane & 15, quad = lane >> 4;
#pragma unroll
    for (int tm = 0; tm < 4; ++tm) {
        float bv[4];
        int   bi[4];
#pragma unroll
        for (int r = 0; r < 4; ++r) { bv[r] = FLT_MAX; bi[r] = 0; }
#pragma unroll
        for (int tn = 0; tn < 4; ++tn) {          // ascending col -> lowest-idx ties
            int c = cs * 128 + wn * 64 + tn * 16 + ln;
            float ec = esq[c];
#pragma unroll
            for (int r = 0; r < 4; ++r) {
                float d = fmaf(-2.f, acc[tm][tn][r], ec);
                if (d < bv[r]) { bv[r] = d; bi[r] = c; }
            }
        }
        int row0 = wm * 64 + tm * 16 + quad * 4;
        int slot = wn * 16 + ln;
#pragma unroll
        for (int r = 0; r < 4; ++r) {
            cv[(row0 + r) * 33 + slot] = bv[r];
            ci[(row0 + r) * 33 + slot] = bi[r];
        }
    }
    __syncthreads();
    if (tid < 128) {
        float bv = cv[tid * 33];
        int   bi = ci[tid * 33];
#pragma unroll
        for (int s = 1; s < 32; ++s) {
            float v = cv[tid * 33 + s];
            int  ix = ci[tid * 33 + s];
            if (v < bv || (v == bv && ix < bi)) { bv = v; bi = ix; }
        }
        u64 key = ((u64)fmap(bv) << 32) | (unsigned)bi;
        atomicMin(&keys[rb * 128 + tid], key);
    }
}

// streaming quantize + straight-through + loss partials + histogram + bi array.
// 2048 blocks x 16 rows; float4 throughout; one int atomic per row. (R4-proven)
__global__ __launch_bounds__(256) void vq_quant(const float* __restrict__ x,
                                                const float* __restrict__ emb,
                                                const u64* __restrict__ keys,
                                                float* __restrict__ outq,
                                                int* __restrict__ cnti,
                                                int* __restrict__ bi_arr,
                                                float* __restrict__ lpart) {
    const int tid = threadIdx.x, lane = tid & 63, w = tid >> 6;
    const float4* x4 = (const float4*)x;
    const float4* e4 = (const float4*)emb;
    float4* o4 = (float4*)outq;
    float lacc = 0.f;
#pragma unroll
    for (int it = 0; it < 4; ++it) {
        int row = blockIdx.x * 16 + it * 4 + w;
        int bi = (int)(unsigned)(keys[row] & 0xffffffffULL);
        if (lane == 0) { atomicAdd(&cnti[bi], 1); bi_arr[row] = bi; }
        float4 xv = x4[row * 64 + lane];
        float4 ev = e4[bi * 64 + lane];
        float4 q;
        q.x = xv.x + (ev.x - xv.x);  q.y = xv.y + (ev.y - xv.y);
        q.z = xv.z + (ev.z - xv.z);  q.w = xv.w + (ev.w - xv.w);
        o4[row * 64 + lane] = q;
        float dx = xv.x - ev.x, dy = xv.y - ev.y, dz = xv.z - ev.z, dwv = xv.w - ev.w;
        lacc += dx * dx + dy * dy + dz * dz + dwv * dwv;
    }
#pragma unroll
    for (int off = 32; off; off >>= 1) lacc += __shfl_xor(lacc, off, 64);
    __shared__ float red[4];
    if (lane == 0) red[w] = lacc;
    __syncthreads();
    if (tid == 0) lpart[blockIdx.x] = red[0] + red[1] + red[2] + red[3];
}

// mega-tail: grid 1024, one block per code m. Replaces scan/fill/finalize/wsum.
// Each block: (a) reduce cnti+ema_count -> n; (b) scan bi_arr for rows of m
// into LDS list; (c) gather-sum those x rows -> dw; (d) write new_count/
// new_weight/new_embedding. Block 0 also computes losses + perplexity.
#define MEGA_CAP 6144
__global__ __launch_bounds__(256) void vq_mega(const float* __restrict__ x,
                                               const float* __restrict__ ema_count,
                                               const float* __restrict__ ema_weight,
                                               const int* __restrict__ cnti,
                                               const int* __restrict__ bi_arr,
                                               const float* __restrict__ lpart,
                                               float* __restrict__ out) {
    const int m = blockIdx.x, tid = threadIdx.x;
    __shared__ float fs[256];
    __shared__ int list[MEGA_CAP];
    __shared__ int lcount;

    // (a) n = sum(DECAY*ema_count + OMD*cnti)  (8 KB, L2-hot, every block)
    float rsum = 0.f;
#pragma unroll
    for (int i = 0; i < 4; ++i) {
        int mm = tid * 4 + i;
        rsum += DECAY_ * ema_count[mm] + OMD_ * (float)cnti[mm];
    }
    fs[tid] = rsum;
    if (tid == 0) lcount = 0;
    __syncthreads();
    for (int s = 128; s; s >>= 1) { if (tid < s) fs[tid] += fs[tid + s]; __syncthreads(); }
    const float n = fs[0];
    __syncthreads();

    // (b)+(c): row list for code m, then deterministic-enough gather-sum
    const int nm = cnti[m];
    float dwsum;
    if (nm <= MEGA_CAP) {
        for (int i = tid; i < N_TOK; i += 256)
            if (bi_arr[i] == m) { int p = atomicAdd(&lcount, 1); list[p] = i; }
        __syncthreads();
        float a0 = 0.f, a1 = 0.f, a2 = 0.f, a3 = 0.f;
        int i = 0;
        for (; i + 4 <= nm; i += 4) {
            a0 += x[list[i]     * DIM + tid];
            a1 += x[list[i + 1] * DIM + tid];
            a2 += x[list[i + 2] * DIM + tid];
            a3 += x[list[i + 3] * DIM + tid];
        }
        for (; i < nm; ++i) a0 += x[list[i] * DIM + tid];
        dwsum = (a0 + a1) + (a2 + a3);
    } else {
        // defensive fallback (not expected with this data distribution)
        __shared__ int chunk[256];
        float a0 = 0.f;
        for (int base = 0; base < N_TOK; base += 256) {
            __syncthreads();
            chunk[tid] = bi_arr[base + tid];
            __syncthreads();
            for (int j = 0; j < 256; ++j)
                if (chunk[j] == m) a0 += x[(base + j) * DIM + tid];
        }
        dwsum = a0;
    }

    // (d) outputs for code m
    float raw_m = DECAY_ * ema_count[m] + OMD_ * (float)nm;
    float ncm = (raw_m + EPS_) / (n + MEPS_) * n;
    float nw = DECAY_ * ema_weight[m * DIM + tid] + OMD_ * dwsum;
    out[OUT_NW + m * DIM + tid] = nw;
    out[OUT_NE + m * DIM + tid] = nw / ncm;
    if (tid == 0) out[OUT_NC + m] = ncm;

    // block 0: entropy -> perplexity; lpart reduce -> losses
    if (m == 0) {
        float ent = 0.f;
#pragma unroll
        for (int i = 0; i < 4; ++i) {
            float p = (float)cnti[tid * 4 + i] / (float)N_TOK;
            ent += p * logf(p + 1e-10f);
        }
        __syncthreads();
        fs[tid] = ent;
        __syncthreads();
        for (int s = 128; s; s >>= 1) { if (tid < s) fs[tid] += fs[tid + s]; __syncthreads(); }
        float entr = fs[0];
        __syncthreads();
        float ls = 0.f;
#pragma unroll
        for (int k = 0; k < 8; ++k) ls += lpart[tid + 256 * k];
        fs[tid] = ls;
        __syncthreads();
        for (int s = 128; s; s >>= 1) { if (tid < s) fs[tid] += fs[tid + s]; __syncthreads(); }
        if (tid == 0) {
            float mean = fs[0] / (float)(N_TOK * DIM);
            out[OUT_COMMIT]   = 0.25f * mean;
            out[OUT_CODEBOOK] = mean;
            out[OUT_PERP]     = expf(-entr);
        }
    }
}

extern "C" void kernel_launch(void* const* d_in, const int* in_sizes, int n_in,
                              void* d_out, int out_size, void* d_ws, size_t ws_size,
                              hipStream_t stream) {
    const float* x          = (const float*)d_in[0];
    const float* emb        = (const float*)d_in[1];
    const float* ema_count  = (const float*)d_in[2];
    const float* ema_weight = (const float*)d_in[3];
    float* out = (float*)d_out;
    float* wf  = (float*)d_ws;

    // xh/xl live in the d_out quantized region (33.5 MB); vq_quant overwrites
    // it afterwards.
    u16* xh = (u16*)d_out;
    u16* xl = xh + (size_t)N_TOK * DIM;
    u16* eh = (u16*)(wf + WS_EH);
    u16* el = (u16*)(wf + WS_EL);

    float* esq    = wf + WS_ESQ;
    int*   cnti   = (int*)(wf + WS_CNTI);
    int*   bi_arr = (int*)(wf + WS_BI);
    float* lpart  = wf + WS_LP;
    u64*   keys   = (u64*)(wf + WS_KEY);

    vq_setup<<<4609, 256, 0, stream>>>(x, emb, xh, xl, eh, el, esq, keys, cnti);
    vq_scores_mfma<<<2048, 256, 0, stream>>>(xh, xl, eh, el, esq, keys);
    vq_quant<<<2048, 256, 0, stream>>>(x, emb, keys, out, cnti, bi_arr, lpart);
    vq_mega<<<MCODE, 256, 0, stream>>>(x, ema_count, ema_weight, cnti, bi_arr,
                                       lpart, out);
}

// Round 7
// 160.770 us; speedup vs baseline: 1.2346x; 1.2346x over previous
//
#include <hip/hip_runtime.h>
#include <cfloat>
#include <math.h>

#define N_TOK 32768
#define DIM   256
#define MCODE 1024

typedef unsigned short u16;
typedef unsigned long long u64;
typedef __attribute__((ext_vector_type(8))) short short8;
typedef __attribute__((ext_vector_type(4))) float f32x4;

constexpr float DECAY_ = 0.999f;
constexpr float OMD_   = (float)(1.0 - 0.999);   // match jax double->f32 promotion
constexpr float EPS_   = 1e-5f;
constexpr float MEPS_  = (float)(1024 * 1e-5);   // M * EPS in double, then f32

// ---- workspace layout (float offsets) ----
// TOTAL = 364544 floats = 1,458,176 B. MUST stay <= 3,284,992 B (Round-1-proven
// ws_size bound) — overflow corrupts harness pristine copies (Round-2 failure).
constexpr int WS_EH   = 0;        // eh[1024*256] bf16 -> 131072 float slots
constexpr int WS_EL   = 131072;   // el           -> 131072
constexpr int WS_ESQ  = 262144;   // esq[1024]
constexpr int WS_CNTI = 263168;   // int counts[1024] (zeroed in setup)
constexpr int WS_BI   = 264192;   // int bi[32768]
constexpr int WS_LP   = 296960;   // loss partials[2048]
constexpr int WS_KEY  = 299008;   // u64 keys[32768] (8B-aligned)

// ---- output layout (float offsets) ----
constexpr int OUT_Q        = 0;
constexpr int OUT_COMMIT   = 8388608;
constexpr int OUT_CODEBOOK = 8388609;
constexpr int OUT_PERP     = 8388610;
constexpr int OUT_NE       = 8388611;
constexpr int OUT_NC       = 8650755;
constexpr int OUT_NW       = 8651779;

static __device__ __forceinline__ u16 f2bf(float f) {
    unsigned u = __float_as_uint(f);
    unsigned r = (u + 0x7fff + ((u >> 16) & 1)) >> 16;   // rn-even
    return (u16)r;
}
static __device__ __forceinline__ float bf2f(u16 h) {
    return __uint_as_float(((unsigned)h) << 16);
}
static __device__ __forceinline__ void gl2lds16(const u16* g, char* l) {
    __builtin_amdgcn_global_load_lds(
        (const __attribute__((address_space(1))) unsigned int*)g,
        (__attribute__((address_space(3))) unsigned int*)l, 16, 0, 0);
}
// monotone float->uint map: a<b  <=>  map(a)<map(b)  (finite floats)
static __device__ __forceinline__ unsigned fmap(float f) {
    unsigned u = __float_as_uint(f);
    return (u & 0x80000000u) ? ~u : (u | 0x80000000u);
}

// MFMA-fragment global order:
// dst[wave*512 + lane*8 + j] <-> src[row=(wave>>6)*128+(wave&7)*16+(lane&15)]
//                                   [k=((wave>>3)&7)*32+(lane>>4)*8+j]
static __device__ __forceinline__ void load_row8(const float* __restrict__ src,
                                                 int wave_id, int lane,
                                                 float* vv, size_t* o) {
    int rb = wave_id >> 6, kc = (wave_id >> 3) & 7, t = wave_id & 7;
    int row = rb * 128 + t * 16 + (lane & 15);
    int k   = kc * 32 + (lane >> 4) * 8;
    const float* s = &src[row * DIM + k];
    float4 v0 = *(const float4*)s, v1 = *(const float4*)(s + 4);
    vv[0]=v0.x; vv[1]=v0.y; vv[2]=v0.z; vv[3]=v0.w;
    vv[4]=v1.x; vv[5]=v1.y; vv[6]=v1.z; vv[7]=v1.w;
    *o = (size_t)wave_id * 512 + lane * 8;
}
// x: hi only (2-MFMA scheme needs no x residual)
static __device__ __forceinline__ void pack_wave_hi(const float* __restrict__ src,
                                                    u16* __restrict__ dh,
                                                    int wave_id, int lane) {
    float vv[8]; size_t o;
    load_row8(src, wave_id, lane, vv, &o);
    short8 hv;
#pragma unroll
    for (int j = 0; j < 8; ++j) hv[j] = (short)f2bf(vv[j]);
    *(short8*)&dh[o] = hv;
}
// e: hi + residual (eh + el == e to ~2^-18 relative)
static __device__ __forceinline__ void pack_wave_hl(const float* __restrict__ src,
                                                    u16* __restrict__ dh,
                                                    u16* __restrict__ dl,
                                                    int wave_id, int lane) {
    float vv[8]; size_t o;
    load_row8(src, wave_id, lane, vv, &o);
    short8 hv, lv;
#pragma unroll
    for (int j = 0; j < 8; ++j) {
        u16 h = f2bf(vv[j]);
        hv[j] = (short)h;
        lv[j] = (short)f2bf(vv[j] - bf2f(h));
    }
    *(short8*)&dh[o] = hv;
    *(short8*)&dl[o] = lv;
}

// fused setup: pack x-hi (blocks 0..4095), pack e hi/lo (+0..127),
// esq (+128..383), keys init (+384..511), counts zero (+512).
__global__ __launch_bounds__(256) void vq_setup(const float* __restrict__ x,
                                                const float* __restrict__ emb,
                                                u16* __restrict__ xh,
                                                u16* __restrict__ eh,
                                                u16* __restrict__ el,
                                                float* __restrict__ esq,
                                                u64* __restrict__ keys,
                                                int* __restrict__ cnti) {
    const int b = blockIdx.x, tid = threadIdx.x;
    const int lane = tid & 63, w = tid >> 6;
    if (b < 4096) { pack_wave_hi(x, xh, b * 4 + w, lane); return; }
    const int p = b - 4096;
    if (p < 128) {
        pack_wave_hl(emb, eh, el, p * 4 + w, lane);
    } else if (p < 384) {
        int c = (p - 128) * 4 + w;
        float4 v = *(const float4*)&emb[c * DIM + lane * 4];
        float s = v.x * v.x + v.y * v.y + v.z * v.z + v.w * v.w;
#pragma unroll
        for (int off = 32; off; off >>= 1) s += __shfl_xor(s, off, 64);
        if (lane == 0) esq[c] = s;
    } else if (p < 512) {
        keys[(p - 384) * 256 + tid] = ~0ULL;
    } else {
#pragma unroll
        for (int i = 0; i < 4; ++i) cnti[i * 256 + tid] = 0;
    }
}

// main MFMA scores+argmin: 2048 blocks; XCD swizzle (R4-proven: FETCH 132->20 MB).
// block = 128 rows x 128 cols, 4 waves 2x2, wave = 4x4 grid of 16x16x32.
// dot = xh*(eh+el) via 2 MFMA (only x rounded; dropped xl*e ~ 9e-6 sigma,
// below the reference's own fp32 x^2-add noise ~3e-5). dist = esq[c] - 2*dot.
__global__ __launch_bounds__(256) void vq_scores_mfma(const u16* __restrict__ xh,
                                                      const u16* __restrict__ eh,
                                                      const u16* __restrict__ el,
                                                      const float* __restrict__ esq,
                                                      u64* __restrict__ keys) {
    __shared__ __align__(16) char smem[33792];
    const int tid  = threadIdx.x;
    const int lane = tid & 63, w = tid >> 6;
    const int wm = w & 1, wn = w >> 1;
    const int raw = blockIdx.x;
    const int rb = (raw >> 6) * 8 + (raw & 7);
    const int cs = (raw >> 3) & 7;

    const u16* gb0 = xh + (size_t)rb * 32768;
    const u16* gb1 = eh + (size_t)cs * 32768;
    const u16* gb2 = el + (size_t)cs * 32768;

    const short8* Ah = (const short8*)(smem);
    const short8* Bh = (const short8*)(smem + 8192);
    const short8* Bl = (const short8*)(smem + 16384);

    f32x4 acc[4][4];
#pragma unroll
    for (int i = 0; i < 4; ++i)
#pragma unroll
        for (int j = 0; j < 4; ++j) acc[i][j] = (f32x4)0.f;

    for (int kc = 0; kc < 8; ++kc) {
        __syncthreads();   // previous chunk's frag reads done before overwrite
        // 24 x 1KB wave-loads per chunk; wave w takes flat indices [6w, 6w+6)
#pragma unroll
        for (int j = 0; j < 6; ++j) {
            int t = w * 6 + j;
            int arr = t >> 3, slot = t & 7;
            const u16* g = (arr == 0 ? gb0 : (arr == 1 ? gb1 : gb2))
                           + kc * 4096 + slot * 512 + lane * 8;
            gl2lds16(g, smem + arr * 8192 + slot * 1024);
        }
        __syncthreads();   // drains vmcnt (incl. global_load_lds) + barrier

        short8 ah[4];
#pragma unroll
        for (int tm = 0; tm < 4; ++tm)
            ah[tm] = Ah[(wm * 4 + tm) * 64 + lane];
#pragma unroll
        for (int tn = 0; tn < 4; ++tn) {
            int bidx = (wn * 4 + tn) * 64 + lane;
            short8 bh = Bh[bidx], bl = Bl[bidx];
#pragma unroll
            for (int tm = 0; tm < 4; ++tm) {
                acc[tm][tn] = __builtin_amdgcn_mfma_f32_16x16x32_bf16(ah[tm], bh, acc[tm][tn], 0, 0, 0);
                acc[tm][tn] = __builtin_amdgcn_mfma_f32_16x16x32_bf16(ah[tm], bl, acc[tm][tn], 0, 0, 0);
            }
        }
    }

    // epilogue: dist = esq - 2*acc, per-row argmin.
    // C/D layout: col = lane&15, row = (lane>>4)*4 + reg (m89/m91-verified)
    __syncthreads();
    float* cv = (float*)smem;            // [128 rows][33 slots] pad -> conflict-free
    int*   ci = (int*)(smem + 16896);
    const int ln = lane & 15, quad = lane >> 4;
#pragma unroll
    for (int tm = 0; tm < 4; ++tm) {
        float bv[4];
        int   bi[4];
#pragma unroll
        for (int r = 0; r < 4; ++r) { bv[r] = FLT_MAX; bi[r] = 0; }
#pragma unroll
        for (int tn = 0; tn < 4; ++tn) {          // ascending col -> lowest-idx ties
            int c = cs * 128 + wn * 64 + tn * 16 + ln;
            float ec = esq[c];
#pragma unroll
            for (int r = 0; r < 4; ++r) {
                float d = fmaf(-2.f, acc[tm][tn][r], ec);
                if (d < bv[r]) { bv[r] = d; bi[r] = c; }
            }
        }
        int row0 = wm * 64 + tm * 16 + quad * 4;
        int slot = wn * 16 + ln;
#pragma unroll
        for (int r = 0; r < 4; ++r) {
            cv[(row0 + r) * 33 + slot] = bv[r];
            ci[(row0 + r) * 33 + slot] = bi[r];
        }
    }
    __syncthreads();
    if (tid < 128) {
        float bv = cv[tid * 33];
        int   bi = ci[tid * 33];
#pragma unroll
        for (int s = 1; s < 32; ++s) {
            float v = cv[tid * 33 + s];
            int  ix = ci[tid * 33 + s];
            if (v < bv || (v == bv && ix < bi)) { bv = v; bi = ix; }
        }
        u64 key = ((u64)fmap(bv) << 32) | (unsigned)bi;
        atomicMin(&keys[rb * 128 + tid], key);
    }
}

// streaming quantize + straight-through + loss partials + histogram + bi array.
// 2048 blocks x 16 rows; float4 throughout; one int atomic per row. (R4-proven)
__global__ __launch_bounds__(256) void vq_quant(const float* __restrict__ x,
                                                const float* __restrict__ emb,
                                                const u64* __restrict__ keys,
                                                float* __restrict__ outq,
                                                int* __restrict__ cnti,
                                                int* __restrict__ bi_arr,
                                                float* __restrict__ lpart) {
    const int tid = threadIdx.x, lane = tid & 63, w = tid >> 6;
    const float4* x4 = (const float4*)x;
    const float4* e4 = (const float4*)emb;
    float4* o4 = (float4*)outq;
    float lacc = 0.f;
#pragma unroll
    for (int it = 0; it < 4; ++it) {
        int row = blockIdx.x * 16 + it * 4 + w;
        int bi = (int)(unsigned)(keys[row] & 0xffffffffULL);
        if (lane == 0) { atomicAdd(&cnti[bi], 1); bi_arr[row] = bi; }
        float4 xv = x4[row * 64 + lane];
        float4 ev = e4[bi * 64 + lane];
        float4 q;
        q.x = xv.x + (ev.x - xv.x);  q.y = xv.y + (ev.y - xv.y);
        q.z = xv.z + (ev.z - xv.z);  q.w = xv.w + (ev.w - xv.w);
        o4[row * 64 + lane] = q;
        float dx = xv.x - ev.x, dy = xv.y - ev.y, dz = xv.z - ev.z, dwv = xv.w - ev.w;
        lacc += dx * dx + dy * dy + dz * dz + dwv * dwv;
    }
#pragma unroll
    for (int off = 32; off; off >>= 1) lacc += __shfl_xor(lacc, off, 64);
    __shared__ float red[4];
    if (lane == 0) red[w] = lacc;
    __syncthreads();
    if (tid == 0) lpart[blockIdx.x] = red[0] + red[1] + red[2] + red[3];
}

// mega-tail: grid 1024, one block per code m.
// int4 + unroll scan (R6's scalar latency-bound scan was ~50 us);
// n via the exact identity sum(counts) == N_TOK -> only ema_count reduced.
#define MEGA_CAP 6144
__global__ __launch_bounds__(256) void vq_mega(const float* __restrict__ x,
                                               const float* __restrict__ ema_count,
                                               const float* __restrict__ ema_weight,
                                               const int* __restrict__ cnti,
                                               const int* __restrict__ bi_arr,
                                               const float* __restrict__ lpart,
                                               float* __restrict__ out) {
    const int m = blockIdx.x, tid = threadIdx.x;
    __shared__ float fs[256];
    __shared__ int list[MEGA_CAP];
    __shared__ int lcount;

    float rsum = 0.f;
#pragma unroll
    for (int i = 0; i < 4; ++i) rsum += ema_count[tid * 4 + i];
    fs[tid] = rsum;
    if (tid == 0) lcount = 0;
    __syncthreads();
    for (int s = 128; s; s >>= 1) { if (tid < s) fs[tid] += fs[tid + s]; __syncthreads(); }
    const float n = DECAY_ * fs[0] + OMD_ * (float)N_TOK;
    __syncthreads();

    // scan bi_arr (int4, unrolled -> loads pipelined) for rows of code m
    const int4* b4 = (const int4*)bi_arr;
#pragma unroll 4
    for (int i = tid; i < N_TOK / 4; i += 256) {
        int4 v = b4[i];
        if (v.x == m) { int p = atomicAdd(&lcount, 1); if (p < MEGA_CAP) list[p] = 4 * i; }
        if (v.y == m) { int p = atomicAdd(&lcount, 1); if (p < MEGA_CAP) list[p] = 4 * i + 1; }
        if (v.z == m) { int p = atomicAdd(&lcount, 1); if (p < MEGA_CAP) list[p] = 4 * i + 2; }
        if (v.w == m) { int p = atomicAdd(&lcount, 1); if (p < MEGA_CAP) list[p] = 4 * i + 3; }
    }
    __syncthreads();
    const int nm = lcount;
    float dwsum;
    if (nm <= MEGA_CAP) {
        float a0 = 0.f, a1 = 0.f, a2 = 0.f, a3 = 0.f;
        int i = 0;
        for (; i + 4 <= nm; i += 4) {
            a0 += x[list[i]     * DIM + tid];
            a1 += x[list[i + 1] * DIM + tid];
            a2 += x[list[i + 2] * DIM + tid];
            a3 += x[list[i + 3] * DIM + tid];
        }
        for (; i < nm; ++i) a0 += x[list[i] * DIM + tid];
        dwsum = (a0 + a1) + (a2 + a3);
    } else {
        // defensive fallback (not expected with this data distribution)
        __shared__ int chunk[256];
        float a0 = 0.f;
        for (int base = 0; base < N_TOK; base += 256) {
            __syncthreads();
            chunk[tid] = bi_arr[base + tid];
            __syncthreads();
            for (int j = 0; j < 256; ++j)
                if (chunk[j] == m) a0 += x[(base + j) * DIM + tid];
        }
        dwsum = a0;
    }

    float raw_m = DECAY_ * ema_count[m] + OMD_ * (float)nm;
    float ncm = (raw_m + EPS_) / (n + MEPS_) * n;
    float nw = DECAY_ * ema_weight[m * DIM + tid] + OMD_ * dwsum;
    out[OUT_NW + m * DIM + tid] = nw;
    out[OUT_NE + m * DIM + tid] = nw / ncm;
    if (tid == 0) out[OUT_NC + m] = ncm;

    if (m == 0) {
        float ent = 0.f;
#pragma unroll
        for (int i = 0; i < 4; ++i) {
            float p = (float)cnti[tid * 4 + i] / (float)N_TOK;
            ent += p * logf(p + 1e-10f);
        }
        __syncthreads();
        fs[tid] = ent;
        __syncthreads();
        for (int s = 128; s; s >>= 1) { if (tid < s) fs[tid] += fs[tid + s]; __syncthreads(); }
        float entr = fs[0];
        __syncthreads();
        float ls = 0.f;
#pragma unroll
        for (int k = 0; k < 8; ++k) ls += lpart[tid + 256 * k];
        fs[tid] = ls;
        __syncthreads();
        for (int s = 128; s; s >>= 1) { if (tid < s) fs[tid] += fs[tid + s]; __syncthreads(); }
        if (tid == 0) {
            float mean = fs[0] / (float)(N_TOK * DIM);
            out[OUT_COMMIT]   = 0.25f * mean;
            out[OUT_CODEBOOK] = mean;
            out[OUT_PERP]     = expf(-entr);
        }
    }
}

extern "C" void kernel_launch(void* const* d_in, const int* in_sizes, int n_in,
                              void* d_out, int out_size, void* d_ws, size_t ws_size,
                              hipStream_t stream) {
    const float* x          = (const float*)d_in[0];
    const float* emb        = (const float*)d_in[1];
    const float* ema_count  = (const float*)d_in[2];
    const float* ema_weight = (const float*)d_in[3];
    float* out = (float*)d_out;
    float* wf  = (float*)d_ws;

    // xh lives in the d_out quantized region (16.8 of 33.5 MB); vq_quant
    // overwrites it afterwards.
    u16* xh = (u16*)d_out;
    u16* eh = (u16*)(wf + WS_EH);
    u16* el = (u16*)(wf + WS_EL);

    float* esq    = wf + WS_ESQ;
    int*   cnti   = (int*)(wf + WS_CNTI);
    int*   bi_arr = (int*)(wf + WS_BI);
    float* lpart  = wf + WS_LP;
    u64*   keys   = (u64*)(wf + WS_KEY);

    vq_setup<<<4609, 256, 0, stream>>>(x, emb, xh, eh, el, esq, keys, cnti);
    vq_scores_mfma<<<2048, 256, 0, stream>>>(xh, eh, el, esq, keys);
    vq_quant<<<2048, 256, 0, stream>>>(x, emb, keys, out, cnti, bi_arr, lpart);
    vq_mega<<<MCODE, 256, 0, stream>>>(x, ema_count, ema_weight, cnti, bi_arr,
                                       lpart, out);
}